// Round 2
// baseline (639.919 us; speedup 1.0000x reference)
//
#include <hip/hip_runtime.h>

#define DEVINL __device__ __forceinline__

typedef __attribute__((ext_vector_type(8))) short short8;
typedef __attribute__((ext_vector_type(4))) float f32x4;

// ---------- helpers ----------
DEVINL unsigned short f2b(float f) {
    union { float f; unsigned u; } v; v.f = f;
    unsigned r = v.u + 0x7fffu + ((v.u >> 16) & 1u);
    return (unsigned short)(r >> 16);
}
DEVINL float b2f(unsigned short u) {
    union { unsigned u; float f; } v; v.u = ((unsigned)u) << 16;
    return v.f;
}
DEVINL void gload_lds16(const unsigned short* g, unsigned short* l) {
    __builtin_amdgcn_global_load_lds(
        (const __attribute__((address_space(1))) void*)g,
        (__attribute__((address_space(3))) void*)l, 16, 0, 0);
}

// ---------- fp32 -> bf16 conversion (vectorized) ----------
__global__ __launch_bounds__(256) void cvt_bf16(const float* __restrict__ in,
                                                unsigned short* __restrict__ out,
                                                long n4) {
    long stride = (long)gridDim.x * blockDim.x;
    for (long i = (long)blockIdx.x * blockDim.x + threadIdx.x; i < n4; i += stride) {
        float4 v = ((const float4*)in)[i];
        ((ushort4*)out)[i] = make_ushort4(f2b(v.x), f2b(v.y), f2b(v.z), f2b(v.w));
    }
}

// Wc[2048][1024] = concat(W_ih, W_gate) rows, bf16
__global__ __launch_bounds__(256) void cvt_wc(const float* __restrict__ Wih,
                                              const float* __restrict__ Wg,
                                              unsigned short* __restrict__ Wc) {
    long i = (long)blockIdx.x * blockDim.x + threadIdx.x;   // 0..524287 (2M/4)
    float4 v = (i < 262144) ? ((const float4*)Wih)[i]
                            : ((const float4*)Wg)[i - 262144];
    ((ushort4*)Wc)[i] = make_ushort4(f2b(v.x), f2b(v.y), f2b(v.z), f2b(v.w));
}

// bc[2048] = concat(b_ih, b_gate); av[1024] = exp(log_a)
__global__ void prep_misc(const float* __restrict__ b_ih, const float* __restrict__ b_gate,
                          const float* __restrict__ log_a, float* __restrict__ bc,
                          float* __restrict__ av) {
    int i = blockIdx.x * blockDim.x + threadIdx.x;
    if (i < 1024) {
        bc[i] = b_ih[i];
        bc[1024 + i] = b_gate[i];
        av[i] = __expf(log_a[i]);
    }
}

// ---------- GEMM: C[M][N] = A[M][K] * Bm[N][K]^T + bias[N]  (m97 structure) ----------
// A, Bm bf16 (K-contiguous rows). 128x128 tile, BK=32, 256 threads (4 waves, 2x2 of 64x64).
template<bool OUT_BF16>
__global__ __launch_bounds__(256)
void gemm_bt(const unsigned short* __restrict__ A, const unsigned short* __restrict__ Bm,
             const float* __restrict__ bias, void* __restrict__ Cout,
             int M, int N, int K) {
    __shared__ __align__(16) unsigned short As[128 * 32];
    __shared__ __align__(16) unsigned short Bs[128 * 32];
    const int tid  = threadIdx.x;
    const int lane = tid & 63;
    const int wave = tid >> 6;
    const int wr = wave >> 1, wc = wave & 1;
    const int nbx = N >> 7;
    const int by = blockIdx.x / nbx;
    const int bx = blockIdx.x % nbx;
    const long rowBase = (long)by * 128;
    const long colBase = (long)bx * 128;

    f32x4 acc[4][4] = {};

    const int off0 = tid * 8;            // element offset of this thread's first 16B chunk
    const int lr = lane & 15;
    const int lk = (lane >> 4) * 8;

    for (int k0 = 0; k0 < K; k0 += 32) {
        {   // stage A tile 128x32
            int off = off0;
            int r = off >> 5, c = off & 31;
            gload_lds16(A + (rowBase + r) * K + k0 + c, As + off);
            off = off0 + 2048;
            r = off >> 5; c = off & 31;
            gload_lds16(A + (rowBase + r) * K + k0 + c, As + off);
        }
        {   // stage B tile 128x32
            int off = off0;
            int r = off >> 5, c = off & 31;
            gload_lds16(Bm + (colBase + r) * K + k0 + c, Bs + off);
            off = off0 + 2048;
            r = off >> 5; c = off & 31;
            gload_lds16(Bm + (colBase + r) * K + k0 + c, Bs + off);
        }
        __syncthreads();
        short8 af[4], bf[4];
#pragma unroll
        for (int m = 0; m < 4; ++m)
            af[m] = *(const short8*)(As + (wr * 64 + m * 16 + lr) * 32 + lk);
#pragma unroll
        for (int n = 0; n < 4; ++n)
            bf[n] = *(const short8*)(Bs + (wc * 64 + n * 16 + lr) * 32 + lk);
#pragma unroll
        for (int m = 0; m < 4; ++m)
#pragma unroll
            for (int n = 0; n < 4; ++n)
                acc[m][n] = __builtin_amdgcn_mfma_f32_16x16x32_bf16(af[m], bf[n], acc[m][n], 0, 0, 0);
        __syncthreads();
    }

    // epilogue: C/D layout col=lane&15, row=(lane>>4)*4+j  (m89-verified)
    const int lr4 = (lane >> 4) * 4;
    const int lc  = lane & 15;
#pragma unroll
    for (int m = 0; m < 4; ++m) {
#pragma unroll
        for (int n = 0; n < 4; ++n) {
            long col = colBase + wc * 64 + n * 16 + lc;
            float bv = bias[col];
#pragma unroll
            for (int j = 0; j < 4; ++j) {
                long row = rowBase + wr * 64 + m * 16 + lr4 + j;
                float v = acc[m][n][j] + bv;
                if (OUT_BF16) ((unsigned short*)Cout)[row * N + col] = f2b(v);
                else          ((float*)Cout)[row * N + col] = v;
            }
        }
    }
}

// ---------- chunked scan over T ----------
// lin[(b*T+t)*2048 + h]      = ih_lin (bias included)
// lin[(b*T+t)*2048 + 1024+h] = gate_lin
// h_t = alpha_t * h_{t-1} + beta_t ; alpha=(1-sig(g))*a[h], beta=sig(g)*ih
// 32 chunks of 256 steps. Thread id: h fastest (coalesced), then b, then chunk.

__global__ __launch_bounds__(256) void scan_a(const unsigned short* __restrict__ lin,
                                              const float* __restrict__ av,
                                              float* __restrict__ cA, float* __restrict__ cB) {
    int tid = blockIdx.x * 256 + threadIdx.x;   // 0..131071
    int h = tid & 1023;
    int r = tid >> 10;
    int b = r & 3;
    int c = r >> 2;                              // 0..31
    int base = ((b * 8192 + c * 256) << 11) + h; // *2048
    float a = av[h];
    float Aa = 1.f, Bv = 0.f;
#pragma unroll 4
    for (int t = 0; t < 256; ++t) {
        float li = b2f(lin[base]);
        float lg = b2f(lin[base + 1024]);
        float gate = 1.f / (1.f + __expf(-lg));
        float alpha = (1.f - gate) * a;
        float beta  = gate * li;
        Aa = alpha * Aa;
        Bv = alpha * Bv + beta;
        base += 2048;
    }
    int idx = (b * 32 + c) * 1024 + h;
    cA[idx] = Aa;
    cB[idx] = Bv;
}

__global__ __launch_bounds__(256) void scan_b(const float* __restrict__ cA,
                                              const float* __restrict__ cB,
                                              float* __restrict__ carry) {
    int tid = blockIdx.x * 256 + threadIdx.x;   // 0..4095
    int h = tid & 1023;
    int b = tid >> 10;
    float hc = 0.f;
    for (int c = 0; c < 32; ++c) {
        int idx = (b * 32 + c) * 1024 + h;
        carry[idx] = hc;
        hc = cA[idx] * hc + cB[idx];
    }
}

__global__ __launch_bounds__(256) void scan_c(const unsigned short* __restrict__ lin,
                                              const float* __restrict__ av,
                                              const float* __restrict__ carry,
                                              unsigned short* __restrict__ hbuf) {
    int tid = blockIdx.x * 256 + threadIdx.x;
    int h = tid & 1023;
    int r = tid >> 10;
    int b = r & 3;
    int c = r >> 2;
    int base  = ((b * 8192 + c * 256) << 11) + h;   // lin index
    int obase = ((b * 8192 + c * 256) << 10) + h;   // hbuf index
    float a = av[h];
    float hc = carry[(b * 32 + c) * 1024 + h];
#pragma unroll 4
    for (int t = 0; t < 256; ++t) {
        float li = b2f(lin[base]);
        float lg = b2f(lin[base + 1024]);
        float gate = 1.f / (1.f + __expf(-lg));
        float alpha = (1.f - gate) * a;
        float beta  = gate * li;
        hc = alpha * hc + beta;
        hbuf[obase] = f2b(hc);
        base += 2048;
        obase += 1024;
    }
}

// ---------- LayerNorm over H=1024, in place on hbuf (bf16) ----------
__global__ __launch_bounds__(256) void ln_k(unsigned short* __restrict__ h,
                                            const float* __restrict__ g,
                                            const float* __restrict__ bt) {
    long row = blockIdx.x;
    int tid = threadIdx.x;
    ushort4 v = ((const ushort4*)(h + row * 1024))[tid];
    float x0 = b2f(v.x), x1 = b2f(v.y), x2 = b2f(v.z), x3 = b2f(v.w);
    float s = x0 + x1 + x2 + x3;
    float q = x0 * x0 + x1 * x1 + x2 * x2 + x3 * x3;
#pragma unroll
    for (int o = 32; o > 0; o >>= 1) {
        s += __shfl_down(s, o);
        q += __shfl_down(q, o);
    }
    __shared__ float ss[4], sq[4];
    int lane = tid & 63, wv = tid >> 6;
    if (lane == 0) { ss[wv] = s; sq[wv] = q; }
    __syncthreads();
    float ts = ss[0] + ss[1] + ss[2] + ss[3];
    float tq = sq[0] + sq[1] + sq[2] + sq[3];
    float mu = ts * (1.f / 1024.f);
    float var = tq * (1.f / 1024.f) - mu * mu;
    float rstd = rsqrtf(var + 1e-5f);
    float4 gv = ((const float4*)g)[tid];
    float4 bv = ((const float4*)bt)[tid];
    ushort4 o;
    o.x = f2b((x0 - mu) * rstd * gv.x + bv.x);
    o.y = f2b((x1 - mu) * rstd * gv.y + bv.y);
    o.z = f2b((x2 - mu) * rstd * gv.z + bv.z);
    o.w = f2b((x3 - mu) * rstd * gv.w + bv.w);
    ((ushort4*)(h + row * 1024))[tid] = o;
}

// ---------- launch ----------
extern "C" void kernel_launch(void* const* d_in, const int* in_sizes, int n_in,
                              void* d_out, int out_size, void* d_ws, size_t ws_size,
                              hipStream_t stream) {
    const float* x      = (const float*)d_in[0];
    const float* W_ih   = (const float*)d_in[1];
    const float* b_ih   = (const float*)d_in[2];
    const float* log_a  = (const float*)d_in[3];
    const float* W_gate = (const float*)d_in[4];
    const float* b_gate = (const float*)d_in[5];
    const float* W_out  = (const float*)d_in[6];
    const float* b_out  = (const float*)d_in[7];
    const float* ln_g   = (const float*)d_in[8];
    const float* ln_b   = (const float*)d_in[9];
    float* out = (float*)d_out;

    char* p = (char*)d_ws;
    size_t off = 0;
    auto take = [&](size_t bytes) {
        char* r = p + off;
        off = (off + bytes + 255) & ~(size_t)255;
        return r;
    };
    unsigned short* xb   = (unsigned short*)take(67108864);    // x bf16      64 MiB
    unsigned short* Wc   = (unsigned short*)take(4194304);     // [2048][1024] bf16
    unsigned short* Wo   = (unsigned short*)take(2097152);     // [1024][1024] bf16
    float*          bc   = (float*)take(8192);                 // bias concat
    float*          av   = (float*)take(4096);                 // exp(log_a)
    unsigned short* lin  = (unsigned short*)take(134217728);   // [32768][2048] bf16
    float*          cA   = (float*)take(524288);
    float*          cB   = (float*)take(524288);
    float*          carry= (float*)take(524288);
    unsigned short* hbuf = (unsigned short*)take(67108864);    // [32768][1024] bf16

    cvt_bf16<<<2048, 256, 0, stream>>>(x, xb, 8388608);
    cvt_wc<<<2048, 256, 0, stream>>>(W_ih, W_gate, Wc);
    cvt_bf16<<<1024, 256, 0, stream>>>(W_out, Wo, 262144);
    prep_misc<<<4, 256, 0, stream>>>(b_ih, b_gate, log_a, bc, av);

    gemm_bt<true><<<4096, 256, 0, stream>>>(xb, Wc, bc, (void*)lin, 32768, 2048, 1024);

    scan_a<<<512, 256, 0, stream>>>(lin, av, cA, cB);
    scan_b<<<16, 256, 0, stream>>>(cA, cB, carry);
    scan_c<<<512, 256, 0, stream>>>(lin, av, carry, hbuf);

    ln_k<<<32768, 256, 0, stream>>>(hbuf, ln_g, ln_b);

    gemm_bt<false><<<2048, 256, 0, stream>>>(hbuf, Wo, b_out, (void*)out, 32768, 1024, 1024);
}